// Round 7
// baseline (326.109 us; speedup 1.0000x reference)
//
#include <hip/hip_runtime.h>
#include <math.h>

#define DM 1024   // d_model
#define NH 16     // heads
#define HD 64     // head dim
#define BB 2      // batch
#define SS 2048   // seq
#define MM (BB*SS)

typedef unsigned short ushort_t;
typedef __attribute__((ext_vector_type(8))) short short8;    // 8 bf16 = MFMA A/B fragment
typedef __attribute__((ext_vector_type(4))) short short4_t;  // 4 bf16 (8B)
typedef __attribute__((ext_vector_type(4))) float floatx4;   // MFMA C/D fragment

// bf16 helpers (round-half-up: 2 VALU ops, <=0.5 ulp)
__device__ __forceinline__ ushort_t f2bf(float f) {
    return (ushort_t)((__float_as_uint(f) + 0x8000u) >> 16);
}
__device__ __forceinline__ float bf2f(ushort_t h) {
    return __uint_as_float(((unsigned int)h) << 16);
}

// async 16B global->LDS (per-lane global addr, wave-uniform LDS base + lane*16)
__device__ __forceinline__ void gl_lds16(const ushort_t* g, ushort_t* l) {
    __builtin_amdgcn_global_load_lds(
        (const __attribute__((address_space(1))) unsigned int*)g,
        (__attribute__((address_space(3))) unsigned int*)l, 16, 0, 0);
}

// ---------------------------------------------------------------------------
// RoPE cos/sin table: ct[s*32+j] = (cos(s*invf(j)), sin(s*invf(j)))
// ---------------------------------------------------------------------------
__global__ __launch_bounds__(256) void freq_kernel(float2* __restrict__ ct)
{
    const int idx = blockIdx.x * 256 + threadIdx.x;   // SS*32
    const int s = idx >> 5, j = idx & 31;
    const float invf = powf(10000.f, -(float)j * (1.f / 32.f));
    float sn, cs;
    sincosf((float)s * invf, &sn, &cs);
    ct[idx] = make_float2(cs, sn);
}

// ---------------------------------------------------------------------------
// Conversions
// ---------------------------------------------------------------------------
__global__ __launch_bounds__(256) void convert_x(const float* __restrict__ X,
                                                 ushort_t* __restrict__ Xh,
                                                 ushort_t* __restrict__ Xl)
{
    const size_t base = ((size_t)blockIdx.x * 256 + threadIdx.x) * 8;
    float v[8];
    *(float4*)&v[0] = *(const float4*)(X + base);
    *(float4*)&v[4] = *(const float4*)(X + base + 4);
    short8 h, l;
#pragma unroll
    for (int i = 0; i < 8; ++i) {
        const ushort_t hi = f2bf(v[i]);
        h[i] = (short)hi;
        l[i] = (short)f2bf(v[i] - bf2f(hi));
    }
    *(short8*)(Xh + base) = h;
    *(short8*)(Xl + base) = l;
}

// All four weights W[k][n] fp32 -> Wt[n][k] bf16 (qw/kw split hi+lo).
__global__ __launch_bounds__(256) void convert_w4(
    const float* __restrict__ qw, const float* __restrict__ kw,
    const float* __restrict__ vw, const float* __restrict__ ow,
    ushort_t* __restrict__ qkh, ushort_t* __restrict__ qkl,
    ushort_t* __restrict__ vwt, ushort_t* __restrict__ owt)
{
    const int which = blockIdx.z;
    const float* W;
    ushort_t *Th, *Tl = nullptr;
    bool split = which < 2;
    if (which == 0)      { W = qw; Th = qkh; Tl = qkl; }
    else if (which == 1) { W = kw; Th = qkh + (size_t)DM * DM; Tl = qkl + (size_t)DM * DM; }
    else if (which == 2) { W = vw; Th = vwt; }
    else                 { W = ow; Th = owt; }

    __shared__ float tile[64][65];
    const int t  = threadIdx.x;
    const int kb = blockIdx.y * 64, nb = blockIdx.x * 64;
    const int r  = t >> 2;
    const int c0 = (t & 3) * 16;
#pragma unroll
    for (int i = 0; i < 4; ++i)
        *(float4*)&tile[r][c0 + 4 * i] = *(const float4*)(W + (size_t)(kb + r) * DM + nb + c0 + 4 * i);
    __syncthreads();
    ushort_t hi[16], lo[16];
#pragma unroll
    for (int i = 0; i < 16; ++i) {
        const float v = tile[c0 + i][r];
        hi[i] = f2bf(v);
        lo[i] = f2bf(v - bf2f(hi[i]));
    }
    const size_t dst = (size_t)(nb + r) * DM + kb + c0;
    *(short8*)(Th + dst)     = *(short8*)&hi[0];
    *(short8*)(Th + dst + 8) = *(short8*)&hi[8];
    if (split) {
        *(short8*)(Tl + dst)     = *(short8*)&lo[0];
        *(short8*)(Tl + dst + 8) = *(short8*)&lo[8];
    }
}

// ---------------------------------------------------------------------------
// MFMA GEMM (double-buffered). OUT_MODE 3 now folds log2(e)/32 into Q so the
// attention softmax can use raw v_exp_f32 (base-2) with no per-element mul.
// ---------------------------------------------------------------------------
#define GTM 128

template<int UPR, int SH>
__device__ __forceinline__ void stage_tile(const ushort_t* __restrict__ G,
                                           ushort_t* L, int rows, int w, int lane)
{
    const int iters = rows * UPR / 256;
#pragma unroll
    for (int i = 0; i < iters; ++i) {
        const int p0 = (i * 4 + w) * 64;
        const int p  = p0 + lane;
        const int r  = p / UPR;
        const int u  = (p % UPR) ^ ((r >> SH) & (UPR - 1));
        gl_lds16(G + (size_t)r * DM + u * 8, L + (size_t)p0 * 8);
    }
}

template<int UPR, int SH>
__device__ __forceinline__ short8 frag(const ushort_t* L, int r, int u)
{
    const int uu = u ^ ((r >> SH) & (UPR - 1));
    return *(const short8*)&L[((size_t)r * UPR + uu) * 8];
}

template<int SPLIT, int OUT_MODE, int TN, int BK>
__global__ __launch_bounds__(256, 2) void gemm_mfma(
    const ushort_t* __restrict__ Ah, const ushort_t* __restrict__ Al,
    const ushort_t* __restrict__ Bh, const ushort_t* __restrict__ Bl,
    float* __restrict__ Cf, ushort_t* __restrict__ Cb, ushort_t* __restrict__ Cb2,
    const float2* __restrict__ CT)
{
    constexpr int UPR = BK / 8;
    constexpr int KC  = BK / 32;
    constexpr int NI  = TN / 32;
    constexpr int SH  = (UPR == 4) ? 1 : 0;
    constexpr int NSTEP = DM / BK;

    __shared__ __align__(16) ushort_t AsH[2][GTM * BK];
    __shared__ __align__(16) ushort_t BsH[2][TN * BK];
    __shared__ __align__(16) ushort_t AsL[2][SPLIT ? GTM * BK : 8];
    __shared__ __align__(16) ushort_t BsL[2][SPLIT ? TN * BK : 8];
    __shared__ __align__(16) ushort_t Ts[(OUT_MODE == 2) ? 64 * 136 : 8];

    const int t    = threadIdx.x;
    const int w    = t >> 6;
    const int lane = t & 63;
    const int col  = lane & 15;
    const int quad = lane >> 4;
    const int wm   = w & 1;
    const int wn   = w >> 1;
    const int m0   = blockIdx.y * GTM;
    const int n0   = blockIdx.x * TN;

    const ushort_t* Abase = Ah + (size_t)m0 * DM;
    const ushort_t* Bbase = Bh + (size_t)n0 * DM;
    const ushort_t* AbaseL = SPLIT ? Al + (size_t)m0 * DM : nullptr;
    const ushort_t* BbaseL = SPLIT ? Bl + (size_t)n0 * DM : nullptr;

    floatx4 acc[4][NI];
#pragma unroll
    for (int mi = 0; mi < 4; ++mi)
#pragma unroll
        for (int ni = 0; ni < NI; ++ni) acc[mi][ni] = (floatx4){0.f, 0.f, 0.f, 0.f};

    stage_tile<UPR, SH>(Abase, AsH[0], GTM, w, lane);
    if (SPLIT) stage_tile<UPR, SH>(AbaseL, AsL[0], GTM, w, lane);
    stage_tile<UPR, SH>(Bbase, BsH[0], TN, w, lane);
    if (SPLIT) stage_tile<UPR, SH>(BbaseL, BsL[0], TN, w, lane);

    for (int ks = 0; ks < NSTEP; ++ks) {
        const int cur = ks & 1;
        __syncthreads();
        if (ks + 1 < NSTEP) {
            const int k1 = (ks + 1) * BK;
            stage_tile<UPR, SH>(Abase + k1, AsH[cur ^ 1], GTM, w, lane);
            if (SPLIT) stage_tile<UPR, SH>(AbaseL + k1, AsL[cur ^ 1], GTM, w, lane);
            stage_tile<UPR, SH>(Bbase + k1, BsH[cur ^ 1], TN, w, lane);
            if (SPLIT) stage_tile<UPR, SH>(BbaseL + k1, BsL[cur ^ 1], TN, w, lane);
        }

#pragma unroll
        for (int kc = 0; kc < KC; ++kc) {
            short8 ah[4], bh[NI];
            short8 al[SPLIT ? 4 : 1], bl[SPLIT ? NI : 1];
#pragma unroll
            for (int mi = 0; mi < 4; ++mi) {
                const int r = wm * 64 + mi * 16 + col;
                ah[mi] = frag<UPR, SH>(AsH[cur], r, kc * 4 + quad);
                if (SPLIT) al[mi] = frag<UPR, SH>(AsL[cur], r, kc * 4 + quad);
            }
#pragma unroll
            for (int ni = 0; ni < NI; ++ni) {
                const int r = wn * (TN / 2) + ni * 16 + col;
                bh[ni] = frag<UPR, SH>(BsH[cur], r, kc * 4 + quad);
                if (SPLIT) bl[ni] = frag<UPR, SH>(BsL[cur], r, kc * 4 + quad);
            }
#pragma unroll
            for (int mi = 0; mi < 4; ++mi)
#pragma unroll
                for (int ni = 0; ni < NI; ++ni) {
                    acc[mi][ni] = __builtin_amdgcn_mfma_f32_16x16x32_bf16(ah[mi], bh[ni], acc[mi][ni], 0, 0, 0);
                    if (SPLIT) {
                        acc[mi][ni] = __builtin_amdgcn_mfma_f32_16x16x32_bf16(al[mi], bh[ni], acc[mi][ni], 0, 0, 0);
                        acc[mi][ni] = __builtin_amdgcn_mfma_f32_16x16x32_bf16(ah[mi], bl[ni], acc[mi][ni], 0, 0, 0);
                    }
                }
        }
    }

    if constexpr (OUT_MODE == 0) {
#pragma unroll
        for (int mi = 0; mi < 4; ++mi)
#pragma unroll
            for (int ni = 0; ni < NI; ++ni)
#pragma unroll
                for (int r = 0; r < 4; ++r) {
                    const int m = m0 + wm * 64 + mi * 16 + quad * 4 + r;
                    const int n = n0 + wn * (TN / 2) + ni * 16 + col;
                    Cf[(size_t)m * DM + n] = acc[mi][ni][r];
                }
    }
    if constexpr (OUT_MODE == 2) {
#pragma unroll
        for (int mi = 0; mi < 4; ++mi)
#pragma unroll
            for (int ni = 0; ni < NI; ++ni) {
                const int nl = wn * (TN / 2) + ni * 16 + col;      // d 0..63
                const int ml = wm * 64 + mi * 16 + quad * 4;       // s-local
                short4_t pk;
#pragma unroll
                for (int r = 0; r < 4; ++r) pk[r] = (short)f2bf(acc[mi][ni][r]);
                *(short4_t*)&Ts[nl * 136 + ml] = pk;
            }
        __syncthreads();
        const int b = m0 >> 11, h = n0 >> 6;
        const int s0 = m0 & (SS - 1);
#pragma unroll
        for (int it = 0; it < 4; ++it) {
            const int idx = it * 256 + t;
            const int dr = idx >> 4, u = idx & 15;
            const short8 v = *(const short8*)&Ts[dr * 136 + u * 8];
            *(short8*)(Cb + ((size_t)((b << 4) + h) * HD + dr) * SS + s0 + u * 8) = v;
        }
    }
    if constexpr (OUT_MODE == 3) {
        const int tn = n0 >> 10;
#pragma unroll
        for (int mi = 0; mi < 4; ++mi)
#pragma unroll
            for (int ni = 0; ni < 2; ++ni)
#pragma unroll
                for (int r = 0; r < 4; ++r) {
                    const int m = m0 + wm * 64 + mi * 16 + quad * 4 + r;
                    const int n = n0 + wn * (TN / 2) + ni * 16 + col;
                    const int b = m >> 11, s = m & (SS - 1);
                    const int h = (n >> 6) & 15, d = n & 63;       // d in 0..31
                    const float2 cs = CT[(s << 5) + d];
                    const float x1 = acc[mi][ni][r];
                    const float x2 = acc[mi][ni + 2][r];
                    const float y1 = x1 * cs.x - x2 * cs.y;
                    const float y2 = x1 * cs.y + x2 * cs.x;
                    const size_t base = ((size_t)((b << 4) + h) * SS + s) * HD + d;
                    if (tn == 0) {
                        // fold score scale AND log2(e): softmax runs in base 2
                        const float qs = 1.442695041f / 32.f;
                        Cf[base]      = y1 * qs;
                        Cf[base + 32] = y2 * qs;
                    } else {
                        const ushort_t h1 = f2bf(y1), h2 = f2bf(y2);
                        Cb [base]      = h1;
                        Cb [base + 32] = h2;
                        Cb2[base]      = f2bf(y1 - bf2f(h1));
                        Cb2[base + 32] = f2bf(y2 - bf2f(h2));
                    }
                }
    }
}

// ---------------------------------------------------------------------------
// MFMA flash attention, split-K, FAT WAVES: 128-thread blocks = 2 waves, each
// wave owns 64 q-rows (mi=4). K/V fragment reads amortize over 2x the q of
// the 32-q/wave version; 40KB LDS keeps 4 blocks/CU possible; z=2 key-halves
// keep the grid at 1024 blocks. Softmax in base 2 (scale pre-folded into Q).
// Writes UN-NORMALIZED bf16 partial O + per-row (m,l); combine merges.
// ---------------------------------------------------------------------------
__device__ __forceinline__ short8 afrag(const ushort_t* S, int r, int lu)
{
    return *(const short8*)&S[(size_t)(((r << 3) | (lu ^ (r & 7))) << 3)];
}

__global__ __launch_bounds__(128, 2) void attn_split(
    const float* __restrict__ Qh, const ushort_t* __restrict__ Khi,
    const ushort_t* __restrict__ Klo, const ushort_t* __restrict__ Vt,
    ushort_t* __restrict__ Op0, ushort_t* __restrict__ Op1,
    float2* __restrict__ ML)
{
    __shared__ __align__(16) ushort_t KhiS[64 * 64];   // [key][dim] 8KB
    __shared__ __align__(16) ushort_t KloS[64 * 64];
    __shared__ __align__(16) ushort_t VtS [64 * 64];   // [dim][key]
    __shared__ __align__(16) ushort_t PS  [128 * 64];  // [qrow][key] 16KB

    const int t    = threadIdx.x;
    const int w    = t >> 6;        // 0..1
    const int lane = t & 63;
    const int col  = lane & 15;
    const int quad = lane >> 4;

    const int bh   = blockIdx.y;
    const int q0   = blockIdx.x * 128;
    const int z    = blockIdx.z;
    const int koff = z * (SS / 2);
    const float*    Qb  = Qh  + (size_t)bh * SS * HD;
    const ushort_t* KhB = Khi + (size_t)bh * SS * HD;
    const ushort_t* KlB = Klo + (size_t)bh * SS * HD;
    const ushort_t* VtB = Vt  + (size_t)bh * HD * SS;

    // Q fragments: wave owns 64 q-rows (4 mi x 16), split hi/lo once
    short8 qhi[4][2], qlo[4][2];
#pragma unroll
    for (int mi = 0; mi < 4; ++mi) {
#pragma unroll
        for (int ch = 0; ch < 2; ++ch) {
            const float* p = Qb + (size_t)(q0 + w * 64 + mi * 16 + col) * HD + ch * 32 + quad * 8;
            const float4 a = *(const float4*)p;
            const float4 b = *(const float4*)(p + 4);
            float v[8] = {a.x, a.y, a.z, a.w, b.x, b.y, b.z, b.w};
#pragma unroll
            for (int j = 0; j < 8; ++j) {
                const ushort_t h = f2bf(v[j]);
                qhi[mi][ch][j] = (short)h;
                qlo[mi][ch][j] = (short)f2bf(v[j] - bf2f(h));
            }
        }
    }

    floatx4 Oacc[4][4];
#pragma unroll
    for (int mi = 0; mi < 4; ++mi)
#pragma unroll
        for (int nt = 0; nt < 4; ++nt) Oacc[mi][nt] = (floatx4){0.f, 0.f, 0.f, 0.f};
    float mstat[4] = {-1e30f, -1e30f, -1e30f, -1e30f};
    float lstat[4] = {0.f, 0.f, 0.f, 0.f};

    for (int kt0 = 0; kt0 < (SS / 2) / 64; ++kt0) {
        const int k0 = koff + kt0 * 64;
        __syncthreads();
        // stage K hi/lo + V^T: pure async DMA, swizzled placement
#pragma unroll
        for (int i = 0; i < 4; ++i) {
            const int p0 = (i * 2 + w) * 64;
            const int p  = p0 + lane;
            const int r  = p >> 3;
            const int gu = (p & 7) ^ (r & 7);
            gl_lds16(KhB + (size_t)(k0 + r) * HD + gu * 8, KhiS + (size_t)p0 * 8);
            gl_lds16(KlB + (size_t)(k0 + r) * HD + gu * 8, KloS + (size_t)p0 * 8);
            gl_lds16(VtB + (size_t)r * SS + k0 + gu * 8,   VtS  + (size_t)p0 * 8);
        }
        __syncthreads();

        // S^T = Khi.Qhi^T + Khi.Qlo^T + Klo.Qhi^T  (C: col=qrow, rows=keys)
        floatx4 sc[4][4];   // [kt][mi]
#pragma unroll
        for (int kt = 0; kt < 4; ++kt) {
            short8 kh[2], kl[2];
#pragma unroll
            for (int ch = 0; ch < 2; ++ch) {
                kh[ch] = afrag(KhiS, kt * 16 + col, ch * 4 + quad);
                kl[ch] = afrag(KloS, kt * 16 + col, ch * 4 + quad);
            }
#pragma unroll
            for (int mi = 0; mi < 4; ++mi) {
                floatx4 a = (floatx4){0.f, 0.f, 0.f, 0.f};
#pragma unroll
                for (int ch = 0; ch < 2; ++ch)
                    a = __builtin_amdgcn_mfma_f32_16x16x32_bf16(kh[ch], qhi[mi][ch], a, 0, 0, 0);
#pragma unroll
                for (int ch = 0; ch < 2; ++ch)
                    a = __builtin_amdgcn_mfma_f32_16x16x32_bf16(kh[ch], qlo[mi][ch], a, 0, 0, 0);
#pragma unroll
                for (int ch = 0; ch < 2; ++ch)
                    a = __builtin_amdgcn_mfma_f32_16x16x32_bf16(kl[ch], qhi[mi][ch], a, 0, 0, 0);
                sc[kt][mi] = a;
            }
        }

        // online softmax, base 2: lane owns qrow = w*64+mi*16+col
#pragma unroll
        for (int mi = 0; mi < 4; ++mi) {
            float mloc = -1e30f;
#pragma unroll
            for (int kt = 0; kt < 4; ++kt)
#pragma unroll
                for (int r = 0; r < 4; ++r) mloc = fmaxf(mloc, sc[kt][mi][r]);
            mloc = fmaxf(mloc, __shfl_xor(mloc, 16));
            mloc = fmaxf(mloc, __shfl_xor(mloc, 32));
            const float mnew  = fmaxf(mstat[mi], mloc);
            const float alpha = __builtin_amdgcn_exp2f(mstat[mi] - mnew);
            mstat[mi] = mnew;

            float psum = 0.f;
            const int qrow = w * 64 + mi * 16 + col;
#pragma unroll
            for (int kt = 0; kt < 4; ++kt) {
                short4_t pk;
#pragma unroll
                for (int r = 0; r < 4; ++r) {
                    const float p = __builtin_amdgcn_exp2f(sc[kt][mi][r] - mnew);
                    psum += p;
                    pk[r] = (short)f2bf(p);
                }
                const int u = (kt * 2 + (quad >> 1)) ^ (col & 7);
                *(short4_t*)&PS[(qrow << 6) + (u << 3) + ((quad & 1) << 2)] = pk;
            }
            psum += __shfl_xor(psum, 16);
            psum += __shfl_xor(psum, 32);
            lstat[mi] = lstat[mi] * alpha + psum;

            floatx4 alr;
#pragma unroll
            for (int r = 0; r < 4; ++r) alr[r] = __shfl(alpha, quad * 4 + r, 64);
#pragma unroll
            for (int nt = 0; nt < 4; ++nt)
#pragma unroll
                for (int r = 0; r < 4; ++r) Oacc[mi][nt][r] *= alr[r];
        }

        // PV (PS rows are wave-local)
        short8 pf[4][2];
#pragma unroll
        for (int mi = 0; mi < 4; ++mi)
#pragma unroll
            for (int ch = 0; ch < 2; ++ch)
                pf[mi][ch] = afrag(PS, w * 64 + mi * 16 + col, ch * 4 + quad);
#pragma unroll
        for (int nt = 0; nt < 4; ++nt) {
            short8 vf[2];
#pragma unroll
            for (int ch = 0; ch < 2; ++ch)
                vf[ch] = afrag(VtS, nt * 16 + col, ch * 4 + quad);
#pragma unroll
            for (int mi = 0; mi < 4; ++mi)
#pragma unroll
                for (int ch = 0; ch < 2; ++ch)
                    Oacc[mi][nt] = __builtin_amdgcn_mfma_f32_16x16x32_bf16(pf[mi][ch], vf[ch], Oacc[mi][nt], 0, 0, 0);
        }
    }

    // epilogue: UN-NORMALIZED partial O -> merged layout [b, s, h*64+d] bf16;
    // per-row (m,l) -> ML[z*32+bh][s].  m is in base-2 units.
    ushort_t* dst = z ? Op1 : Op0;
    const int b = bh >> 4, h = bh & 15;
#pragma unroll
    for (int mi = 0; mi < 4; ++mi) {
#pragma unroll
        for (int nt = 0; nt < 4; ++nt)
#pragma unroll
            for (int r = 0; r < 4; ++r) {
                const int srow = q0 + w * 64 + mi * 16 + quad * 4 + r;
                dst[(size_t)(b * SS + srow) * DM + h * HD + nt * 16 + col] =
                    f2bf(Oacc[mi][nt][r]);
            }
        if (quad == 0) {
            const int srow = q0 + w * 64 + mi * 16 + col;
            ML[((size_t)z * 32 + bh) * SS + srow] = make_float2(mstat[mi], lstat[mi]);
        }
    }
}

// ---------------------------------------------------------------------------
// Combine the two key-half partials (base-2 stats):
// out = (s0*O0 + s1*O1) / (s0*l0 + s1*l1), s_z = exp2(m_z - max(m0,m1)).
// ---------------------------------------------------------------------------
__global__ __launch_bounds__(256) void attn_combine(
    ushort_t* __restrict__ Op0, const ushort_t* __restrict__ Op1,
    const float2* __restrict__ ML)
{
    const size_t idx8 = ((size_t)blockIdx.x * 256 + threadIdx.x) * 8;  // over MM*DM
    const int row  = (int)(idx8 >> 10);       // b*SS + s
    const int hcol = (int)(idx8 & 1023);
    const int h = hcol >> 6;
    const int b = row >> 11, s = row & (SS - 1);
    const int bh = (b << 4) + h;

    const float2 ml0 = ML[(size_t)bh * SS + s];
    const float2 ml1 = ML[((size_t)32 + bh) * SS + s];
    const float m  = fmaxf(ml0.x, ml1.x);
    const float s0 = __builtin_amdgcn_exp2f(ml0.x - m);
    const float s1 = __builtin_amdgcn_exp2f(ml1.x - m);
    const float inv = 1.f / (s0 * ml0.y + s1 * ml1.y);

    const short8 a = *(const short8*)(Op0 + idx8);
    const short8 c = *(const short8*)(Op1 + idx8);
    short8 o;
#pragma unroll
    for (int i = 0; i < 8; ++i)
        o[i] = (short)f2bf((s0 * bf2f((ushort_t)a[i]) + s1 * bf2f((ushort_t)c[i])) * inv);
    *(short8*)(Op0 + idx8) = o;
}

// ---------------------------------------------------------------------------
extern "C" void kernel_launch(void* const* d_in, const int* in_sizes, int n_in,
                              void* d_out, int out_size, void* d_ws, size_t ws_size,
                              hipStream_t stream)
{
    const float* x  = (const float*)d_in[0];
    const float* qw = (const float*)d_in[1];
    const float* kw = (const float*)d_in[2];
    const float* vw = (const float*)d_in[3];
    const float* ow = (const float*)d_in[4];
    float* out = (float*)d_out;

    // ws layout (~76.5 MB). xh/xl are dead after the projection GEMMs and are
    // reused by attention: Op1 partial aliases xh, (m,l) stats alias xl.
    float*    Qh  = (float*)d_ws;                       // 16 MB fp32 head-major (rope'd, x log2e/32)
    ushort_t* Khi = (ushort_t*)(Qh + (size_t)MM * DM);  // 8 MB bf16 head-major (rope'd)
    ushort_t* Klo = Khi + (size_t)MM * DM;              // 8 MB
    ushort_t* Vtb = Klo + (size_t)MM * DM;              // 8 MB bf16 [b,h,d,s]
    ushort_t* Mgb = Vtb + (size_t)MM * DM;              // 8 MB bf16 merged (= Op0)
    ushort_t* xh  = Mgb + (size_t)MM * DM;              // 8 MB (-> Op1 after GEMMs)
    ushort_t* xl  = xh  + (size_t)MM * DM;              // 8 MB (-> ML after GEMMs)
    ushort_t* qkh = xl  + (size_t)MM * DM;              // 4 MB [2048][1024]
    ushort_t* qkl = qkh + (size_t)2048 * DM;            // 4 MB
    ushort_t* vwt = qkl + (size_t)2048 * DM;            // 2 MB
    ushort_t* owt = vwt + (size_t)DM * DM;              // 2 MB
    float2*   ct  = (float2*)(owt + (size_t)DM * DM);   // 0.5 MB

    ushort_t* Op1 = xh;
    float2*   ML  = (float2*)xl;                        // 1 MB used

    freq_kernel<<<(SS * 32) / 256, 256, 0, stream>>>(ct);
    convert_x<<<(MM * DM) / (256 * 8), 256, 0, stream>>>(x, xh, xl);
    convert_w4<<<dim3(16, 16, 4), 256, 0, stream>>>(qw, kw, vw, ow, qkh, qkl, vwt, owt);

    // fused Q|K projection + RoPE: split-bf16 3-term
    gemm_mfma<1, 3, 128, 32><<<dim3(2048 / 128, MM / GTM), 256, 0, stream>>>(
        xh, xl, qkh, qkl, Qh, Khi, Klo, ct);
    // V projection -> transposed bf16 [b,h,d,s]
    gemm_mfma<0, 2, 64, 64><<<dim3(DM / 64, MM / GTM), 256, 0, stream>>>(
        xh, nullptr, vwt, nullptr, nullptr, Vtb, nullptr, nullptr);

    // split-K attention: 128-thread fat-wave blocks, z key-halves
    attn_split<<<dim3(SS / 128, BB * NH, 2), 128, 0, stream>>>(
        Qh, Khi, Klo, Vtb, Mgb, Op1, ML);
    attn_combine<<<(MM * DM) / (256 * 8), 256, 0, stream>>>(Mgb, Op1, ML);

    // out projection
    gemm_mfma<0, 0, 64, 64><<<dim3(DM / 64, MM / GTM), 256, 0, stream>>>(
        Mgb, nullptr, owt, nullptr, out, nullptr, nullptr, nullptr);
}

// Round 9
// 262.318 us; speedup vs baseline: 1.2432x; 1.2432x over previous
//
#include <hip/hip_runtime.h>
#include <math.h>

#define DM 1024   // d_model
#define NH 16     // heads
#define HD 64     // head dim
#define BB 2      // batch
#define SS 2048   // seq
#define MM (BB*SS)

typedef unsigned short ushort_t;
typedef __attribute__((ext_vector_type(8))) short short8;    // 8 bf16 = MFMA A/B fragment
typedef __attribute__((ext_vector_type(4))) short short4_t;  // 4 bf16 (8B)
typedef __attribute__((ext_vector_type(4))) float floatx4;   // MFMA C/D fragment

// bf16 helpers (round-half-up: 2 VALU ops, <=0.5 ulp)
__device__ __forceinline__ ushort_t f2bf(float f) {
    return (ushort_t)((__float_as_uint(f) + 0x8000u) >> 16);
}
__device__ __forceinline__ float bf2f(ushort_t h) {
    return __uint_as_float(((unsigned int)h) << 16);
}

// async 16B global->LDS (per-lane global addr, wave-uniform LDS base + lane*16)
__device__ __forceinline__ void gl_lds16(const ushort_t* g, ushort_t* l) {
    __builtin_amdgcn_global_load_lds(
        (const __attribute__((address_space(1))) unsigned int*)g,
        (__attribute__((address_space(3))) unsigned int*)l, 16, 0, 0);
}

// ---------------------------------------------------------------------------
// RoPE cos/sin table: ct[s*32+j] = (cos(s*invf(j)), sin(s*invf(j)))
// ---------------------------------------------------------------------------
__global__ __launch_bounds__(256) void freq_kernel(float2* __restrict__ ct)
{
    const int idx = blockIdx.x * 256 + threadIdx.x;   // SS*32
    const int s = idx >> 5, j = idx & 31;
    const float invf = powf(10000.f, -(float)j * (1.f / 32.f));
    float sn, cs;
    sincosf((float)s * invf, &sn, &cs);
    ct[idx] = make_float2(cs, sn);
}

// ---------------------------------------------------------------------------
// Conversions
// ---------------------------------------------------------------------------
__global__ __launch_bounds__(256) void convert_x(const float* __restrict__ X,
                                                 ushort_t* __restrict__ Xh,
                                                 ushort_t* __restrict__ Xl)
{
    const size_t base = ((size_t)blockIdx.x * 256 + threadIdx.x) * 8;
    float v[8];
    *(float4*)&v[0] = *(const float4*)(X + base);
    *(float4*)&v[4] = *(const float4*)(X + base + 4);
    short8 h, l;
#pragma unroll
    for (int i = 0; i < 8; ++i) {
        const ushort_t hi = f2bf(v[i]);
        h[i] = (short)hi;
        l[i] = (short)f2bf(v[i] - bf2f(hi));
    }
    *(short8*)(Xh + base) = h;
    *(short8*)(Xl + base) = l;
}

// All four weights W[k][n] fp32 -> Wt[n][k] bf16 (qw/kw split hi+lo).
__global__ __launch_bounds__(256) void convert_w4(
    const float* __restrict__ qw, const float* __restrict__ kw,
    const float* __restrict__ vw, const float* __restrict__ ow,
    ushort_t* __restrict__ qkh, ushort_t* __restrict__ qkl,
    ushort_t* __restrict__ vwt, ushort_t* __restrict__ owt)
{
    const int which = blockIdx.z;
    const float* W;
    ushort_t *Th, *Tl = nullptr;
    bool split = which < 2;
    if (which == 0)      { W = qw; Th = qkh; Tl = qkl; }
    else if (which == 1) { W = kw; Th = qkh + (size_t)DM * DM; Tl = qkl + (size_t)DM * DM; }
    else if (which == 2) { W = vw; Th = vwt; }
    else                 { W = ow; Th = owt; }

    __shared__ float tile[64][65];
    const int t  = threadIdx.x;
    const int kb = blockIdx.y * 64, nb = blockIdx.x * 64;
    const int r  = t >> 2;
    const int c0 = (t & 3) * 16;
#pragma unroll
    for (int i = 0; i < 4; ++i)
        *(float4*)&tile[r][c0 + 4 * i] = *(const float4*)(W + (size_t)(kb + r) * DM + nb + c0 + 4 * i);
    __syncthreads();
    ushort_t hi[16], lo[16];
#pragma unroll
    for (int i = 0; i < 16; ++i) {
        const float v = tile[c0 + i][r];
        hi[i] = f2bf(v);
        lo[i] = f2bf(v - bf2f(hi[i]));
    }
    const size_t dst = (size_t)(nb + r) * DM + kb + c0;
    *(short8*)(Th + dst)     = *(short8*)&hi[0];
    *(short8*)(Th + dst + 8) = *(short8*)&hi[8];
    if (split) {
        *(short8*)(Tl + dst)     = *(short8*)&lo[0];
        *(short8*)(Tl + dst + 8) = *(short8*)&lo[8];
    }
}

// ---------------------------------------------------------------------------
// MFMA GEMM — round-4 SINGLE-BUFFERED version (dbuf measured -9us regression).
// C[M x N] = A[M x K] @ Bt[N x K]^T, bf16 (optional hi+lo 3-term), fp32 acc.
// OUT_MODE: 0 flat fp32 | 2 V: bf16 transposed head-major [b,h,d,s] via LDS
//           | 3 fused QK+RoPE: Q fp32 head-major (x log2e/32 -> base-2
//             softmax downstream), K bf16 hi/lo head-major
// ---------------------------------------------------------------------------
#define GTM 128

template<int UPR, int SH>
__device__ __forceinline__ void stage_tile(const ushort_t* __restrict__ G,
                                           ushort_t* L, int rows, int w, int lane)
{
    const int iters = rows * UPR / 256;
#pragma unroll
    for (int i = 0; i < iters; ++i) {
        const int p0 = (i * 4 + w) * 64;
        const int p  = p0 + lane;
        const int r  = p / UPR;
        const int u  = (p % UPR) ^ ((r >> SH) & (UPR - 1));
        gl_lds16(G + (size_t)r * DM + u * 8, L + (size_t)p0 * 8);
    }
}

template<int UPR, int SH>
__device__ __forceinline__ short8 frag(const ushort_t* L, int r, int u)
{
    const int uu = u ^ ((r >> SH) & (UPR - 1));
    return *(const short8*)&L[((size_t)r * UPR + uu) * 8];
}

template<int SPLIT, int OUT_MODE, int TN, int BK>
__global__ __launch_bounds__(256, 2) void gemm_mfma(
    const ushort_t* __restrict__ Ah, const ushort_t* __restrict__ Al,
    const ushort_t* __restrict__ Bh, const ushort_t* __restrict__ Bl,
    float* __restrict__ Cf, ushort_t* __restrict__ Cb, ushort_t* __restrict__ Cb2,
    const float2* __restrict__ CT)
{
    constexpr int UPR = BK / 8;
    constexpr int KC  = BK / 32;
    constexpr int NI  = TN / 32;
    constexpr int SH  = (UPR == 4) ? 1 : 0;

    __shared__ __align__(16) ushort_t AsH[GTM * BK];
    __shared__ __align__(16) ushort_t BsH[TN * BK];
    __shared__ __align__(16) ushort_t AsL[SPLIT ? GTM * BK : 8];
    __shared__ __align__(16) ushort_t BsL[SPLIT ? TN * BK : 8];
    __shared__ __align__(16) ushort_t Ts[(OUT_MODE == 2) ? 64 * 136 : 8];

    const int t    = threadIdx.x;
    const int w    = t >> 6;
    const int lane = t & 63;
    const int col  = lane & 15;
    const int quad = lane >> 4;
    const int wm   = w & 1;
    const int wn   = w >> 1;
    const int m0   = blockIdx.y * GTM;
    const int n0   = blockIdx.x * TN;

    floatx4 acc[4][NI];
#pragma unroll
    for (int mi = 0; mi < 4; ++mi)
#pragma unroll
        for (int ni = 0; ni < NI; ++ni) acc[mi][ni] = (floatx4){0.f, 0.f, 0.f, 0.f};

    for (int k0 = 0; k0 < DM; k0 += BK) {
        __syncthreads();
        stage_tile<UPR, SH>(Ah + (size_t)m0 * DM + k0, AsH, GTM, w, lane);
        if (SPLIT) stage_tile<UPR, SH>(Al + (size_t)m0 * DM + k0, AsL, GTM, w, lane);
        stage_tile<UPR, SH>(Bh + (size_t)n0 * DM + k0, BsH, TN, w, lane);
        if (SPLIT) stage_tile<UPR, SH>(Bl + (size_t)n0 * DM + k0, BsL, TN, w, lane);
        __syncthreads();

#pragma unroll
        for (int kc = 0; kc < KC; ++kc) {
            short8 ah[4], bh[NI];
            short8 al[SPLIT ? 4 : 1], bl[SPLIT ? NI : 1];
#pragma unroll
            for (int mi = 0; mi < 4; ++mi) {
                const int r = wm * 64 + mi * 16 + col;
                ah[mi] = frag<UPR, SH>(AsH, r, kc * 4 + quad);
                if (SPLIT) al[mi] = frag<UPR, SH>(AsL, r, kc * 4 + quad);
            }
#pragma unroll
            for (int ni = 0; ni < NI; ++ni) {
                const int r = wn * (TN / 2) + ni * 16 + col;
                bh[ni] = frag<UPR, SH>(BsH, r, kc * 4 + quad);
                if (SPLIT) bl[ni] = frag<UPR, SH>(BsL, r, kc * 4 + quad);
            }
#pragma unroll
            for (int mi = 0; mi < 4; ++mi)
#pragma unroll
                for (int ni = 0; ni < NI; ++ni) {
                    acc[mi][ni] = __builtin_amdgcn_mfma_f32_16x16x32_bf16(ah[mi], bh[ni], acc[mi][ni], 0, 0, 0);
                    if (SPLIT) {
                        acc[mi][ni] = __builtin_amdgcn_mfma_f32_16x16x32_bf16(al[mi], bh[ni], acc[mi][ni], 0, 0, 0);
                        acc[mi][ni] = __builtin_amdgcn_mfma_f32_16x16x32_bf16(ah[mi], bl[ni], acc[mi][ni], 0, 0, 0);
                    }
                }
        }
    }

    // ---- epilogues (C/D layout: col=lane&15, row=quad*4+reg) ----
    if constexpr (OUT_MODE == 0) {
#pragma unroll
        for (int mi = 0; mi < 4; ++mi)
#pragma unroll
            for (int ni = 0; ni < NI; ++ni)
#pragma unroll
                for (int r = 0; r < 4; ++r) {
                    const int m = m0 + wm * 64 + mi * 16 + quad * 4 + r;
                    const int n = n0 + wn * (TN / 2) + ni * 16 + col;
                    Cf[(size_t)m * DM + n] = acc[mi][ni][r];
                }
    }
    if constexpr (OUT_MODE == 2) {
#pragma unroll
        for (int mi = 0; mi < 4; ++mi)
#pragma unroll
            for (int ni = 0; ni < NI; ++ni) {
                const int nl = wn * (TN / 2) + ni * 16 + col;      // d 0..63
                const int ml = wm * 64 + mi * 16 + quad * 4;       // s-local
                short4_t pk;
#pragma unroll
                for (int r = 0; r < 4; ++r) pk[r] = (short)f2bf(acc[mi][ni][r]);
                *(short4_t*)&Ts[nl * 136 + ml] = pk;
            }
        __syncthreads();
        const int b = m0 >> 11, h = n0 >> 6;
        const int s0 = m0 & (SS - 1);
#pragma unroll
        for (int it = 0; it < 4; ++it) {
            const int idx = it * 256 + t;
            const int dr = idx >> 4, u = idx & 15;
            const short8 v = *(const short8*)&Ts[dr * 136 + u * 8];
            *(short8*)(Cb + ((size_t)((b << 4) + h) * HD + dr) * SS + s0 + u * 8) = v;
        }
    }
    if constexpr (OUT_MODE == 3) {
        const int tn = n0 >> 10;
#pragma unroll
        for (int mi = 0; mi < 4; ++mi)
#pragma unroll
            for (int ni = 0; ni < 2; ++ni)
#pragma unroll
                for (int r = 0; r < 4; ++r) {
                    const int m = m0 + wm * 64 + mi * 16 + quad * 4 + r;
                    const int n = n0 + wn * (TN / 2) + ni * 16 + col;
                    const int b = m >> 11, s = m & (SS - 1);
                    const int h = (n >> 6) & 15, d = n & 63;       // d in 0..31
                    const float2 cs = CT[(s << 5) + d];
                    const float x1 = acc[mi][ni][r];
                    const float x2 = acc[mi][ni + 2][r];
                    const float y1 = x1 * cs.x - x2 * cs.y;
                    const float y2 = x1 * cs.y + x2 * cs.x;
                    const size_t base = ((size_t)((b << 4) + h) * SS + s) * HD + d;
                    if (tn == 0) {
                        // fold score scale AND log2(e): softmax runs in base 2
                        const float qs = 1.442695041f / 32.f;
                        Cf[base]      = y1 * qs;
                        Cf[base + 32] = y2 * qs;
                    } else {
                        const ushort_t h1 = f2bf(y1), h2 = f2bf(y2);
                        Cb [base]      = h1;
                        Cb [base + 32] = h2;
                        Cb2[base]      = f2bf(y1 - bf2f(h1));
                        Cb2[base + 32] = f2bf(y2 - bf2f(h2));
                    }
                }
    }
}

// ---------------------------------------------------------------------------
// MFMA flash attention, split-K over keys (round-6 winning shape: 256 thr,
// 4 waves, 32 q/wave, z=2 key-halves, 40KB LDS). Base-2 softmax (log2e/32
// folded into Q). Writes UN-NORMALIZED bf16 partial O + (m,l); combine merges.
// ---------------------------------------------------------------------------
__device__ __forceinline__ short8 afrag(const ushort_t* S, int r, int lu)
{
    return *(const short8*)&S[(size_t)(((r << 3) | (lu ^ (r & 7))) << 3)];
}

__global__ __launch_bounds__(256, 2) void attn_split(
    const float* __restrict__ Qh, const ushort_t* __restrict__ Khi,
    const ushort_t* __restrict__ Klo, const ushort_t* __restrict__ Vt,
    ushort_t* __restrict__ Op0, ushort_t* __restrict__ Op1,
    float2* __restrict__ ML)
{
    __shared__ __align__(16) ushort_t KhiS[64 * 64];   // [key][dim] 8KB
    __shared__ __align__(16) ushort_t KloS[64 * 64];
    __shared__ __align__(16) ushort_t VtS [64 * 64];   // [dim][key]
    __shared__ __align__(16) ushort_t PS  [128 * 64];  // [qrow][key] 16KB

    const int t    = threadIdx.x;
    const int w    = t >> 6;
    const int lane = t & 63;
    const int col  = lane & 15;
    const int quad = lane >> 4;

    const int bh   = blockIdx.y;
    const int q0   = blockIdx.x * 128;
    const int z    = blockIdx.z;
    const int koff = z * (SS / 2);
    const float*    Qb  = Qh  + (size_t)bh * SS * HD;
    const ushort_t* KhB = Khi + (size_t)bh * SS * HD;
    const ushort_t* KlB = Klo + (size_t)bh * SS * HD;
    const ushort_t* VtB = Vt  + (size_t)bh * HD * SS;

    // Q fragments (wave's 32 qrows), split hi/lo once
    short8 qhi[2][2], qlo[2][2];
#pragma unroll
    for (int mi = 0; mi < 2; ++mi) {
#pragma unroll
        for (int ch = 0; ch < 2; ++ch) {
            const float* p = Qb + (size_t)(q0 + w * 32 + mi * 16 + col) * HD + ch * 32 + quad * 8;
            const float4 a = *(const float4*)p;
            const float4 b = *(const float4*)(p + 4);
            float v[8] = {a.x, a.y, a.z, a.w, b.x, b.y, b.z, b.w};
#pragma unroll
            for (int j = 0; j < 8; ++j) {
                const ushort_t h = f2bf(v[j]);
                qhi[mi][ch][j] = (short)h;
                qlo[mi][ch][j] = (short)f2bf(v[j] - bf2f(h));
            }
        }
    }

    floatx4 Oacc[2][4];
#pragma unroll
    for (int mi = 0; mi < 2; ++mi)
#pragma unroll
        for (int nt = 0; nt < 4; ++nt) Oacc[mi][nt] = (floatx4){0.f, 0.f, 0.f, 0.f};
    float mstat[2] = {-1e30f, -1e30f}, lstat[2] = {0.f, 0.f};

    for (int kt0 = 0; kt0 < (SS / 2) / 64; ++kt0) {
        const int k0 = koff + kt0 * 64;
        __syncthreads();
        // stage K hi/lo + V^T: pure async DMA, swizzled placement
#pragma unroll
        for (int i = 0; i < 2; ++i) {
            const int p0 = w * 128 + i * 64;
            const int p  = p0 + lane;
            const int r  = p >> 3;
            const int gu = (p & 7) ^ (r & 7);
            gl_lds16(KhB + (size_t)(k0 + r) * HD + gu * 8, KhiS + (size_t)p0 * 8);
            gl_lds16(KlB + (size_t)(k0 + r) * HD + gu * 8, KloS + (size_t)p0 * 8);
            gl_lds16(VtB + (size_t)r * SS + k0 + gu * 8,   VtS  + (size_t)p0 * 8);
        }
        __syncthreads();

        // S^T = Khi.Qhi^T + Khi.Qlo^T + Klo.Qhi^T  (C: col=qrow, rows=keys)
        floatx4 sc[4][2];
#pragma unroll
        for (int kt = 0; kt < 4; ++kt) {
            short8 kh[2], kl[2];
#pragma unroll
            for (int ch = 0; ch < 2; ++ch) {
                kh[ch] = afrag(KhiS, kt * 16 + col, ch * 4 + quad);
                kl[ch] = afrag(KloS, kt * 16 + col, ch * 4 + quad);
            }
#pragma unroll
            for (int mi = 0; mi < 2; ++mi) {
                floatx4 a = (floatx4){0.f, 0.f, 0.f, 0.f};
#pragma unroll
                for (int ch = 0; ch < 2; ++ch)
                    a = __builtin_amdgcn_mfma_f32_16x16x32_bf16(kh[ch], qhi[mi][ch], a, 0, 0, 0);
#pragma unroll
                for (int ch = 0; ch < 2; ++ch)
                    a = __builtin_amdgcn_mfma_f32_16x16x32_bf16(kh[ch], qlo[mi][ch], a, 0, 0, 0);
#pragma unroll
                for (int ch = 0; ch < 2; ++ch)
                    a = __builtin_amdgcn_mfma_f32_16x16x32_bf16(kl[ch], qhi[mi][ch], a, 0, 0, 0);
                sc[kt][mi] = a;
            }
        }

        // online softmax, base 2: lane owns qrow = w*32+mi*16+col
#pragma unroll
        for (int mi = 0; mi < 2; ++mi) {
            float mloc = -1e30f;
#pragma unroll
            for (int kt = 0; kt < 4; ++kt)
#pragma unroll
                for (int r = 0; r < 4; ++r) mloc = fmaxf(mloc, sc[kt][mi][r]);
            mloc = fmaxf(mloc, __shfl_xor(mloc, 16));
            mloc = fmaxf(mloc, __shfl_xor(mloc, 32));
            const float mnew  = fmaxf(mstat[mi], mloc);
            const float alpha = __builtin_amdgcn_exp2f(mstat[mi] - mnew);
            mstat[mi] = mnew;

            float psum = 0.f;
            const int qrow = w * 32 + mi * 16 + col;
#pragma unroll
            for (int kt = 0; kt < 4; ++kt) {
                short4_t pk;
#pragma unroll
                for (int r = 0; r < 4; ++r) {
                    const float p = __builtin_amdgcn_exp2f(sc[kt][mi][r] - mnew);
                    psum += p;
                    pk[r] = (short)f2bf(p);
                }
                const int u = (kt * 2 + (quad >> 1)) ^ (col & 7);
                *(short4_t*)&PS[(qrow << 6) + (u << 3) + ((quad & 1) << 2)] = pk;
            }
            psum += __shfl_xor(psum, 16);
            psum += __shfl_xor(psum, 32);
            lstat[mi] = lstat[mi] * alpha + psum;

            floatx4 alr;
#pragma unroll
            for (int r = 0; r < 4; ++r) alr[r] = __shfl(alpha, quad * 4 + r, 64);
#pragma unroll
            for (int nt = 0; nt < 4; ++nt)
#pragma unroll
                for (int r = 0; r < 4; ++r) Oacc[mi][nt][r] *= alr[r];
        }

        // PV (PS rows are wave-local)
        short8 pf[2][2];
#pragma unroll
        for (int mi = 0; mi < 2; ++mi)
#pragma unroll
            for (int ch = 0; ch < 2; ++ch)
                pf[mi][ch] = afrag(PS, w * 32 + mi * 16 + col, ch * 4 + quad);
#pragma unroll
        for (int nt = 0; nt < 4; ++nt) {
            short8 vf[2];
#pragma unroll
            for (int ch = 0; ch < 2; ++ch)
                vf[ch] = afrag(VtS, nt * 16 + col, ch * 4 + quad);
#pragma unroll
            for (int mi = 0; mi < 2; ++mi)
#pragma unroll
                for (int ch = 0; ch < 2; ++ch)
                    Oacc[mi][nt] = __builtin_amdgcn_mfma_f32_16x16x32_bf16(pf[mi][ch], vf[ch], Oacc[mi][nt], 0, 0, 0);
        }
    }

    // epilogue: UN-NORMALIZED partial O -> merged layout [b, s, h*64+d] bf16;
    // (m,l) -> ML[z*32+bh][s].  m is in base-2 units.
    ushort_t* dst = z ? Op1 : Op0;
    const int b = bh >> 4, h = bh & 15;
#pragma unroll
    for (int mi = 0; mi < 2; ++mi) {
#pragma unroll
        for (int nt = 0; nt < 4; ++nt)
#pragma unroll
            for (int r = 0; r < 4; ++r) {
                const int srow = q0 + w * 32 + mi * 16 + quad * 4 + r;
                dst[(size_t)(b * SS + srow) * DM + h * HD + nt * 16 + col] =
                    f2bf(Oacc[mi][nt][r]);
            }
        if (quad == 0) {
            const int srow = q0 + w * 32 + mi * 16 + col;
            ML[((size_t)z * 32 + bh) * SS + srow] = make_float2(mstat[mi], lstat[mi]);
        }
    }
}

// ---------------------------------------------------------------------------
// Combine the two key-half partials (base-2 stats):
// out = (s0*O0 + s1*O1) / (s0*l0 + s1*l1), s_z = exp2(m_z - max(m0,m1)).
// ---------------------------------------------------------------------------
__global__ __launch_bounds__(256) void attn_combine(
    ushort_t* __restrict__ Op0, const ushort_t* __restrict__ Op1,
    const float2* __restrict__ ML)
{
    const size_t idx8 = ((size_t)blockIdx.x * 256 + threadIdx.x) * 8;  // over MM*DM
    const int row  = (int)(idx8 >> 10);       // b*SS + s
    const int hcol = (int)(idx8 & 1023);
    const int h = hcol >> 6;
    const int b = row >> 11, s = row & (SS - 1);
    const int bh = (b << 4) + h;

    const float2 ml0 = ML[(size_t)bh * SS + s];
    const float2 ml1 = ML[((size_t)32 + bh) * SS + s];
    const float m  = fmaxf(ml0.x, ml1.x);
    const float s0 = __builtin_amdgcn_exp2f(ml0.x - m);
    const float s1 = __builtin_amdgcn_exp2f(ml1.x - m);
    const float inv = 1.f / (s0 * ml0.y + s1 * ml1.y);

    const short8 a = *(const short8*)(Op0 + idx8);
    const short8 c = *(const short8*)(Op1 + idx8);
    short8 o;
#pragma unroll
    for (int i = 0; i < 8; ++i)
        o[i] = (short)f2bf((s0 * bf2f((ushort_t)a[i]) + s1 * bf2f((ushort_t)c[i])) * inv);
    *(short8*)(Op0 + idx8) = o;
}

// ---------------------------------------------------------------------------
extern "C" void kernel_launch(void* const* d_in, const int* in_sizes, int n_in,
                              void* d_out, int out_size, void* d_ws, size_t ws_size,
                              hipStream_t stream)
{
    const float* x  = (const float*)d_in[0];
    const float* qw = (const float*)d_in[1];
    const float* kw = (const float*)d_in[2];
    const float* vw = (const float*)d_in[3];
    const float* ow = (const float*)d_in[4];
    float* out = (float*)d_out;

    // ws layout (~76.5 MB). xh/xl are dead after the projection GEMMs and are
    // reused by attention: Op1 partial aliases xh, (m,l) stats alias xl.
    float*    Qh  = (float*)d_ws;                       // 16 MB fp32 head-major (rope'd, x log2e/32)
    ushort_t* Khi = (ushort_t*)(Qh + (size_t)MM * DM);  // 8 MB bf16 head-major (rope'd)
    ushort_t* Klo = Khi + (size_t)MM * DM;              // 8 MB
    ushort_t* Vtb = Klo + (size_t)MM * DM;              // 8 MB bf16 [b,h,d,s]
    ushort_t* Mgb = Vtb + (size_t)MM * DM;              // 8 MB bf16 merged (= Op0)
    ushort_t* xh  = Mgb + (size_t)MM * DM;              // 8 MB (-> Op1 after GEMMs)
    ushort_t* xl  = xh  + (size_t)MM * DM;              // 8 MB (-> ML after GEMMs)
    ushort_t* qkh = xl  + (size_t)MM * DM;              // 4 MB [2048][1024]
    ushort_t* qkl = qkh + (size_t)2048 * DM;            // 4 MB
    ushort_t* vwt = qkl + (size_t)2048 * DM;            // 2 MB
    ushort_t* owt = vwt + (size_t)DM * DM;              // 2 MB
    float2*   ct  = (float2*)(owt + (size_t)DM * DM);   // 0.5 MB

    ushort_t* Op1 = xh;
    float2*   ML  = (float2*)xl;                        // 1 MB used

    freq_kernel<<<(SS * 32) / 256, 256, 0, stream>>>(ct);
    convert_x<<<(MM * DM) / (256 * 8), 256, 0, stream>>>(x, xh, xl);
    convert_w4<<<dim3(16, 16, 4), 256, 0, stream>>>(qw, kw, vw, ow, qkh, qkl, vwt, owt);

    // fused Q|K projection + RoPE: split-bf16 3-term
    gemm_mfma<1, 3, 128, 32><<<dim3(2048 / 128, MM / GTM), 256, 0, stream>>>(
        xh, xl, qkh, qkl, Qh, Khi, Klo, ct);
    // V projection -> transposed bf16 [b,h,d,s]
    gemm_mfma<0, 2, 64, 64><<<dim3(DM / 64, MM / GTM), 256, 0, stream>>>(
        xh, nullptr, vwt, nullptr, nullptr, Vtb, nullptr, nullptr);

    // split-K attention (256-thr blocks, z = key halves); combine
    attn_split<<<dim3(SS / 128, BB * NH, 2), 256, 0, stream>>>(
        Qh, Khi, Klo, Vtb, Mgb, Op1, ML);
    attn_combine<<<(MM * DM) / (256 * 8), 256, 0, stream>>>(Mgb, Op1, ML);

    // out projection
    gemm_mfma<0, 0, 64, 64><<<dim3(DM / 64, MM / GTM), 256, 0, stream>>>(
        Mgb, nullptr, owt, nullptr, out, nullptr, nullptr, nullptr);
}